// Round 1
// baseline (13353.836 us; speedup 1.0000x reference)
//
#include <hip/hip_runtime.h>
#include <math.h>

#define NEG_SLOPE 0.2f
__device__ __forceinline__ float lrelu(float x) { return x > 0.f ? x : NEG_SLOPE * x; }

// Order-preserving float<->uint encoding so unsigned atomicMax == float max.
__device__ __forceinline__ unsigned encf(float f) {
    unsigned u = __float_as_uint(f);
    return (u & 0x80000000u) ? ~u : (u | 0x80000000u);
}
__device__ __forceinline__ float decf(unsigned u) {
    return __uint_as_float((u & 0x80000000u) ? (u ^ 0x80000000u) : ~u);
}

// ---------------- Layer 1 ----------------
// Phase A: h1 = x @ W1 [N,64]; alpha_src/dst [N,4]; seed emax1 with self-loop logit.
// 64 lanes per node: lane = head*16 + c.
__global__ void phaseA(const float* __restrict__ x, const float* __restrict__ W1,
                       const float* __restrict__ a_src, const float* __restrict__ a_dst,
                       float* __restrict__ h1, float* __restrict__ asrc1,
                       float* __restrict__ adst1, float* __restrict__ eloop1,
                       unsigned* __restrict__ emax1, int N) {
    int node = blockIdx.x * 4 + (threadIdx.x >> 6);
    if (node >= N) return;
    int lane = threadIdx.x & 63;
    int head = lane >> 4, c = lane & 15;

    float h = 0.f;
    #pragma unroll
    for (int k = 0; k < 7; k++) h += x[node * 7 + k] * W1[k * 64 + lane];
    h1[node * 64 + lane] = h;

    float s = h * a_src[lane];   // a_src is [4][16] flat == lane
    float d = h * a_dst[lane];
    #pragma unroll
    for (int m = 8; m >= 1; m >>= 1) {
        s += __shfl_xor(s, m);
        d += __shfl_xor(d, m);
    }
    if (c == 0) {
        asrc1[node * 4 + head] = s;
        adst1[node * 4 + head] = d;
        float el = lrelu(s + d);
        eloop1[node * 4 + head] = el;
        emax1[node * 4 + head] = encf(el);   // self-loop seeds the segment max
    }
}

// Phase B: per (edge, head) atomicMax of edge logit into emax1[dst].
__global__ void phaseB(const int* __restrict__ src, const int* __restrict__ dst,
                       const float* __restrict__ asrc1, const float* __restrict__ adst1,
                       unsigned* __restrict__ emax1, int E) {
    int t = blockIdx.x * blockDim.x + threadIdx.x;
    int idx = t >> 2, h = t & 3;
    if (idx >= E) return;
    int s = src[idx], d = dst[idx];
    float e = lrelu(asrc1[s * 4 + h] + adst1[d * 4 + h]);
    atomicMax(&emax1[d * 4 + h], encf(e));
}

// Phase C1: decode max; init acc1 = ez_loop * h1[n], denom1 = ez_loop.
__global__ void phaseC1(const float* __restrict__ h1, const float* __restrict__ eloop1,
                        const unsigned* __restrict__ emax1, float* __restrict__ emax1f,
                        float* __restrict__ acc1, float* __restrict__ denom1, int N) {
    int node = blockIdx.x * 4 + (threadIdx.x >> 6);
    if (node >= N) return;
    int lane = threadIdx.x & 63;
    int head = lane >> 4, c = lane & 15;
    float m = decf(emax1[node * 4 + head]);
    float ez = expf(eloop1[node * 4 + head] - m);
    acc1[node * 64 + lane] = ez * h1[node * 64 + lane];
    if (c == 0) {
        denom1[node * 4 + head] = ez;
        emax1f[node * 4 + head] = m;
    }
}

// Phase C2: per (edge, head): ez = exp(e - max[dst]); accumulate denom and ez*h1[src].
__global__ void phaseC2(const int* __restrict__ src, const int* __restrict__ dst,
                        const float* __restrict__ asrc1, const float* __restrict__ adst1,
                        const float* __restrict__ emax1f, const float* __restrict__ h1,
                        float* __restrict__ acc1, float* __restrict__ denom1, int E) {
    int t = blockIdx.x * blockDim.x + threadIdx.x;
    int idx = t >> 2, h = t & 3;
    if (idx >= E) return;
    int s = src[idx], d = dst[idx];
    float e = lrelu(asrc1[s * 4 + h] + adst1[d * 4 + h]);
    float ez = expf(e - emax1f[d * 4 + h]);
    atomicAdd(&denom1[d * 4 + h], ez);
    const float4* hp = (const float4*)&h1[s * 64 + h * 16];
    float* ap = &acc1[d * 64 + h * 16];
    #pragma unroll
    for (int q = 0; q < 4; q++) {
        float4 v = hp[q];
        atomicAdd(ap + q * 4 + 0, ez * v.x);
        atomicAdd(ap + q * 4 + 1, ez * v.y);
        atomicAdd(ap + q * 4 + 2, ez * v.z);
        atomicAdd(ap + q * 4 + 3, ez * v.w);
    }
}

// Phase D: out1 = acc1/denom1 + b1; ELU; h2 = elu @ W2 [N,6]; layer-2 logits; seed emax2.
__global__ void phaseD(const float* __restrict__ acc1, const float* __restrict__ denom1,
                       const float* __restrict__ b1, const float* __restrict__ W2,
                       const float* __restrict__ a_src2, const float* __restrict__ a_dst2,
                       float* __restrict__ h2, float* __restrict__ asrc2,
                       float* __restrict__ adst2, float* __restrict__ eloop2,
                       unsigned* __restrict__ emax2, int N) {
    int node = blockIdx.x * 4 + (threadIdx.x >> 6);
    if (node >= N) return;
    int lane = threadIdx.x & 63;
    int head = lane >> 4;
    float v = acc1[node * 64 + lane] / denom1[node * 4 + head] + b1[lane];
    v = v > 0.f ? v : expf(v) - 1.f;   // ELU(alpha=1)

    float hh[6];
    #pragma unroll
    for (int c2 = 0; c2 < 6; c2++) {
        float p = v * W2[lane * 6 + c2];
        #pragma unroll
        for (int m = 32; m >= 1; m >>= 1) p += __shfl_xor(p, m);
        hh[c2] = p;   // all lanes hold full sum
    }
    float as = 0.f, ad = 0.f;
    #pragma unroll
    for (int c2 = 0; c2 < 6; c2++) {
        as += hh[c2] * a_src2[c2];
        ad += hh[c2] * a_dst2[c2];
    }
    if (lane == 0) {
        #pragma unroll
        for (int c2 = 0; c2 < 6; c2++) h2[node * 6 + c2] = hh[c2];
        asrc2[node] = as;
        adst2[node] = ad;
        float el = lrelu(as + ad);
        eloop2[node] = el;
        emax2[node] = encf(el);
    }
}

// Phase E: layer-2 edge max.
__global__ void phaseE(const int* __restrict__ src, const int* __restrict__ dst,
                       const float* __restrict__ asrc2, const float* __restrict__ adst2,
                       unsigned* __restrict__ emax2, int E) {
    int idx = blockIdx.x * blockDim.x + threadIdx.x;
    if (idx >= E) return;
    int s = src[idx], d = dst[idx];
    float e = lrelu(asrc2[s] + adst2[d]);
    atomicMax(&emax2[d], encf(e));
}

// Phase F1: init layer-2 accumulators with self-loop.
__global__ void phaseF1(const float* __restrict__ h2, const float* __restrict__ eloop2,
                        const unsigned* __restrict__ emax2, float* __restrict__ emax2f,
                        float* __restrict__ acc2, float* __restrict__ denom2, int N) {
    int n = blockIdx.x * blockDim.x + threadIdx.x;
    if (n >= N) return;
    float m = decf(emax2[n]);
    float ez = expf(eloop2[n] - m);
    emax2f[n] = m;
    denom2[n] = ez;
    #pragma unroll
    for (int c = 0; c < 6; c++) acc2[n * 6 + c] = ez * h2[n * 6 + c];
}

// Phase F2: layer-2 edge accumulate.
__global__ void phaseF2(const int* __restrict__ src, const int* __restrict__ dst,
                        const float* __restrict__ asrc2, const float* __restrict__ adst2,
                        const float* __restrict__ emax2f, const float* __restrict__ h2,
                        float* __restrict__ acc2, float* __restrict__ denom2, int E) {
    int idx = blockIdx.x * blockDim.x + threadIdx.x;
    if (idx >= E) return;
    int s = src[idx], d = dst[idx];
    float e = lrelu(asrc2[s] + adst2[d]);
    float ez = expf(e - emax2f[d]);
    atomicAdd(&denom2[d], ez);
    #pragma unroll
    for (int c = 0; c < 6; c++) atomicAdd(&acc2[d * 6 + c], ez * h2[s * 6 + c]);
}

// Phase G: normalize, +b2, log_softmax over 6 classes.
__global__ void phaseG(const float* __restrict__ acc2, const float* __restrict__ denom2,
                       const float* __restrict__ b2, float* __restrict__ out, int N) {
    int n = blockIdx.x * blockDim.x + threadIdx.x;
    if (n >= N) return;
    float den = denom2[n];
    float v[6];
    float mx = -1e30f;
    #pragma unroll
    for (int c = 0; c < 6; c++) {
        v[c] = acc2[n * 6 + c] / den + b2[c];
        mx = fmaxf(mx, v[c]);
    }
    float s = 0.f;
    #pragma unroll
    for (int c = 0; c < 6; c++) s += expf(v[c] - mx);
    float lse = mx + logf(s);
    #pragma unroll
    for (int c = 0; c < 6; c++) out[n * 6 + c] = v[c] - lse;
}

extern "C" void kernel_launch(void* const* d_in, const int* in_sizes, int n_in,
                              void* d_out, int out_size, void* d_ws, size_t ws_size,
                              hipStream_t stream) {
    const float* x      = (const float*)d_in[0];
    const int*   ei     = (const int*)d_in[1];
    const float* W1     = (const float*)d_in[2];
    const float* a_src1 = (const float*)d_in[3];
    const float* a_dst1 = (const float*)d_in[4];
    const float* b1     = (const float*)d_in[5];
    const float* W2     = (const float*)d_in[6];
    const float* a_src2 = (const float*)d_in[7];
    const float* a_dst2 = (const float*)d_in[8];
    const float* b2     = (const float*)d_in[9];
    float* out = (float*)d_out;

    const int N = in_sizes[0] / 7;
    const int E = in_sizes[1] / 2;
    const int* src = ei;
    const int* dst = ei + E;

    // Workspace layout (floats). Total = 170*N floats = 68 MB @ N=100k.
    float* w = (float*)d_ws;
    float*    h1     = w;            w += (size_t)N * 64;
    float*    acc1   = w;            w += (size_t)N * 64;
    float*    asrc1  = w;            w += (size_t)N * 4;
    float*    adst1  = w;            w += (size_t)N * 4;
    float*    eloop1 = w;            w += (size_t)N * 4;
    float*    denom1 = w;            w += (size_t)N * 4;
    unsigned* emax1  = (unsigned*)w; w += (size_t)N * 4;
    float*    emax1f = w;            w += (size_t)N * 4;
    float*    h2     = w;            w += (size_t)N * 6;
    float*    acc2   = w;            w += (size_t)N * 6;
    float*    asrc2  = w;            w += (size_t)N;
    float*    adst2  = w;            w += (size_t)N;
    float*    eloop2 = w;            w += (size_t)N;
    float*    denom2 = w;            w += (size_t)N;
    unsigned* emax2  = (unsigned*)w; w += (size_t)N;
    float*    emax2f = w;            w += (size_t)N;

    const int B = 256;
    dim3 gNode((N + 3) / 4);            // 4 nodes per 256-thread block
    dim3 gN((N + B - 1) / B);
    dim3 gE((E + B - 1) / B);
    dim3 gE4(((E * 4) + B - 1) / B);    // thread per (edge, head)

    phaseA<<<gNode, B, 0, stream>>>(x, W1, a_src1, a_dst1, h1, asrc1, adst1, eloop1, emax1, N);
    phaseB<<<gE4, B, 0, stream>>>(src, dst, asrc1, adst1, emax1, E);
    phaseC1<<<gNode, B, 0, stream>>>(h1, eloop1, emax1, emax1f, acc1, denom1, N);
    phaseC2<<<gE4, B, 0, stream>>>(src, dst, asrc1, adst1, emax1f, h1, acc1, denom1, E);
    phaseD<<<gNode, B, 0, stream>>>(acc1, denom1, b1, W2, a_src2, a_dst2,
                                    h2, asrc2, adst2, eloop2, emax2, N);
    phaseE<<<gE, B, 0, stream>>>(src, dst, asrc2, adst2, emax2, E);
    phaseF1<<<gN, B, 0, stream>>>(h2, eloop2, emax2, emax2f, acc2, denom2, N);
    phaseF2<<<gE, B, 0, stream>>>(src, dst, asrc2, adst2, emax2f, h2, acc2, denom2, E);
    phaseG<<<gN, B, 0, stream>>>(acc2, denom2, b2, out, N);
}

// Round 2
// 743.375 us; speedup vs baseline: 17.9638x; 17.9638x over previous
//
#include <hip/hip_runtime.h>
#include <math.h>

#define NEG_SLOPE 0.2f
__device__ __forceinline__ float lrelu(float x) { return x > 0.f ? x : NEG_SLOPE * x; }

__global__ void zeroInts(int* __restrict__ p, int n) {
    int i = blockIdx.x * blockDim.x + threadIdx.x;
    if (i < n) p[i] = 0;
}

// Phase A: h1 = x @ W1 [N,64]; alpha_src/dst [N,4]; self-loop logit.
// 64 lanes per node: lane = head*16 + c.
__global__ void phaseA(const float* __restrict__ x, const float* __restrict__ W1,
                       const float* __restrict__ a_src, const float* __restrict__ a_dst,
                       float* __restrict__ h1, float* __restrict__ asrc1,
                       float* __restrict__ adst1, float* __restrict__ eloop1, int N) {
    int node = blockIdx.x * 4 + (threadIdx.x >> 6);
    if (node >= N) return;
    int lane = threadIdx.x & 63;
    int head = lane >> 4, c = lane & 15;

    float h = 0.f;
    #pragma unroll
    for (int k = 0; k < 7; k++) h += x[node * 7 + k] * W1[k * 64 + lane];
    h1[node * 64 + lane] = h;

    float s = h * a_src[lane];
    float d = h * a_dst[lane];
    #pragma unroll
    for (int m = 8; m >= 1; m >>= 1) {
        s += __shfl_xor(s, m);
        d += __shfl_xor(d, m);
    }
    if (c == 0) {
        asrc1[node * 4 + head] = s;
        adst1[node * 4 + head] = d;
        eloop1[node * 4 + head] = lrelu(s + d);
    }
}

__global__ void degCount(const int* __restrict__ dst, int* __restrict__ deg, int E) {
    int i = blockIdx.x * blockDim.x + threadIdx.x;
    if (i < E) atomicAdd(&deg[dst[i]], 1);
}

// Exclusive scan, 3 kernels. scan1: per-256-block scan; scan2: scan block sums
// (single 1024-thread block, supports up to 1024 blocks = 262144 nodes);
// scan3: add block offsets.
__global__ void scan1(const int* __restrict__ deg, int* __restrict__ rowstart,
                      int* __restrict__ blockSum, int N) {
    __shared__ int sm[256];
    int tid = threadIdx.x;
    int i = blockIdx.x * 256 + tid;
    int v = (i < N) ? deg[i] : 0;
    sm[tid] = v;
    __syncthreads();
    for (int off = 1; off < 256; off <<= 1) {
        int t = sm[tid];
        int add = (tid >= off) ? sm[tid - off] : 0;
        __syncthreads();
        sm[tid] = t + add;
        __syncthreads();
    }
    if (i < N) rowstart[i] = sm[tid] - v;     // exclusive
    if (tid == 255) blockSum[blockIdx.x] = sm[255];
}

__global__ void scan2(int* __restrict__ blockSum, int nb) {
    __shared__ int sm[1024];
    int tid = threadIdx.x;
    int v = (tid < nb) ? blockSum[tid] : 0;
    sm[tid] = v;
    __syncthreads();
    for (int off = 1; off < 1024; off <<= 1) {
        int t = sm[tid];
        int add = (tid >= off) ? sm[tid - off] : 0;
        __syncthreads();
        sm[tid] = t + add;
        __syncthreads();
    }
    if (tid < nb) blockSum[tid] = sm[tid] - v;  // exclusive
}

__global__ void scan3(int* __restrict__ rowstart, const int* __restrict__ blockSum, int N) {
    int i = blockIdx.x * 256 + threadIdx.x;
    if (i < N) rowstart[i] += blockSum[blockIdx.x];
}

__global__ void scatter(const int* __restrict__ src, const int* __restrict__ dst,
                        const int* __restrict__ rowstart, int* __restrict__ cursor,
                        int* __restrict__ csr, int E) {
    int i = blockIdx.x * blockDim.x + threadIdx.x;
    if (i >= E) return;
    int d = dst[i];
    int pos = atomicAdd(&cursor[d], 1);
    csr[rowstart[d] + pos] = src[i];
}

// Layer-1 gather: wave per node. Computes per-head max, then denom + acc in
// registers, then fuses old phaseD: normalize, +b1, ELU, @W2, layer-2 logits.
__global__ void gatherL1(const int* __restrict__ csr, const int* __restrict__ rowstart,
                         const int* __restrict__ deg,
                         const float* __restrict__ h1, const float* __restrict__ asrc1,
                         const float* __restrict__ adst1, const float* __restrict__ eloop1,
                         const float* __restrict__ b1, const float* __restrict__ W2,
                         const float* __restrict__ a_src2, const float* __restrict__ a_dst2,
                         float* __restrict__ h2, float* __restrict__ asrc2,
                         float* __restrict__ adst2, float* __restrict__ eloop2, int N) {
    int node = blockIdx.x * 4 + (threadIdx.x >> 6);
    if (node >= N) return;
    int lane = threadIdx.x & 63;
    int head = lane >> 4, c = lane & 15;
    int rs = rowstart[node], dg = deg[node];
    int ke = rs + dg;

    float adh = adst1[node * 4 + head];
    float el = eloop1[node * 4 + head];

    // pass 1: per-head max (16 lanes of each head stride the edge list)
    float mx = el;
    for (int k = rs + c; k < ke; k += 16) {
        int s = csr[k];
        mx = fmaxf(mx, lrelu(asrc1[s * 4 + head] + adh));
    }
    #pragma unroll
    for (int m = 8; m >= 1; m >>= 1) mx = fmaxf(mx, __shfl_xor(mx, m));

    // pass 2: every lane walks all edges; lane owns channel (head,c)
    float z0 = __expf(el - mx);
    float den = z0;
    float acc = z0 * h1[node * 64 + lane];
    for (int k = rs; k < ke; k++) {
        int s = csr[k];
        float e = lrelu(asrc1[s * 4 + head] + adh);
        float z = __expf(e - mx);
        den += z;                       // redundant across the 16 lanes of a head
        acc += z * h1[s * 64 + lane];   // coalesced 256B row read
    }

    float v = acc / den + b1[lane];
    v = v > 0.f ? v : __expf(v) - 1.f;  // ELU

    // fused old phaseD: h2 = v @ W2 (64->6) via full-wave shfl reductions
    float hh[6];
    #pragma unroll
    for (int c2 = 0; c2 < 6; c2++) {
        float p = v * W2[lane * 6 + c2];
        #pragma unroll
        for (int m = 32; m >= 1; m >>= 1) p += __shfl_xor(p, m);
        hh[c2] = p;
    }
    float as = 0.f, ad = 0.f;
    #pragma unroll
    for (int c2 = 0; c2 < 6; c2++) {
        as += hh[c2] * a_src2[c2];
        ad += hh[c2] * a_dst2[c2];
    }
    if (lane == 0) {
        #pragma unroll
        for (int c2 = 0; c2 < 6; c2++) h2[node * 6 + c2] = hh[c2];
        asrc2[node] = as;
        adst2[node] = ad;
        eloop2[node] = lrelu(as + ad);
    }
}

// Layer-2 gather + log_softmax, wave per node, lanes stride edges.
__global__ void gatherL2(const int* __restrict__ csr, const int* __restrict__ rowstart,
                         const int* __restrict__ deg,
                         const float* __restrict__ h2, const float* __restrict__ asrc2,
                         const float* __restrict__ adst2, const float* __restrict__ eloop2,
                         const float* __restrict__ b2, float* __restrict__ out, int N) {
    int node = blockIdx.x * 4 + (threadIdx.x >> 6);
    if (node >= N) return;
    int lane = threadIdx.x & 63;
    int rs = rowstart[node], dg = deg[node];
    int ke = rs + dg;

    float adn = adst2[node];
    float el = eloop2[node];

    float mx = el;
    for (int k = rs + lane; k < ke; k += 64) {
        int s = csr[k];
        mx = fmaxf(mx, lrelu(asrc2[s] + adn));
    }
    #pragma unroll
    for (int m = 32; m >= 1; m >>= 1) mx = fmaxf(mx, __shfl_xor(mx, m));

    float den = 0.f;
    float acc[6] = {0.f, 0.f, 0.f, 0.f, 0.f, 0.f};
    if (lane == 0) {
        float z = __expf(el - mx);
        den = z;
        #pragma unroll
        for (int cc = 0; cc < 6; cc++) acc[cc] = z * h2[node * 6 + cc];
    }
    for (int k = rs + lane; k < ke; k += 64) {
        int s = csr[k];
        float z = __expf(lrelu(asrc2[s] + adn) - mx);
        den += z;
        #pragma unroll
        for (int cc = 0; cc < 6; cc++) acc[cc] += z * h2[s * 6 + cc];
    }
    #pragma unroll
    for (int m = 32; m >= 1; m >>= 1) {
        den += __shfl_xor(den, m);
        #pragma unroll
        for (int cc = 0; cc < 6; cc++) acc[cc] += __shfl_xor(acc[cc], m);
    }
    if (lane == 0) {
        float v[6];
        float mxv = -1e30f;
        #pragma unroll
        for (int cc = 0; cc < 6; cc++) {
            v[cc] = acc[cc] / den + b2[cc];
            mxv = fmaxf(mxv, v[cc]);
        }
        float ssum = 0.f;
        #pragma unroll
        for (int cc = 0; cc < 6; cc++) ssum += __expf(v[cc] - mxv);
        float lse = mxv + logf(ssum);
        #pragma unroll
        for (int cc = 0; cc < 6; cc++) out[node * 6 + cc] = v[cc] - lse;
    }
}

extern "C" void kernel_launch(void* const* d_in, const int* in_sizes, int n_in,
                              void* d_out, int out_size, void* d_ws, size_t ws_size,
                              hipStream_t stream) {
    const float* x      = (const float*)d_in[0];
    const int*   ei     = (const int*)d_in[1];
    const float* W1     = (const float*)d_in[2];
    const float* a_src1 = (const float*)d_in[3];
    const float* a_dst1 = (const float*)d_in[4];
    const float* b1     = (const float*)d_in[5];
    const float* W2     = (const float*)d_in[6];
    const float* a_src2 = (const float*)d_in[7];
    const float* a_dst2 = (const float*)d_in[8];
    const float* b2     = (const float*)d_in[9];
    float* out = (float*)d_out;

    const int N = in_sizes[0] / 7;
    const int E = in_sizes[1] / 2;
    const int* src = ei;
    const int* dst = ei + E;

    // Workspace layout
    float* w = (float*)d_ws;
    float* h1     = w;  w += (size_t)N * 64;
    float* asrc1  = w;  w += (size_t)N * 4;
    float* adst1  = w;  w += (size_t)N * 4;
    float* eloop1 = w;  w += (size_t)N * 4;
    float* h2     = w;  w += (size_t)N * 6;
    float* asrc2  = w;  w += (size_t)N;
    float* adst2  = w;  w += (size_t)N;
    float* eloop2 = w;  w += (size_t)N;
    int* ip = (int*)w;
    int* deg      = ip; ip += N;      // deg & cursor contiguous -> one zero pass
    int* cursor   = ip; ip += N;
    int* rowstart = ip; ip += N;
    int* blockSum = ip; ip += 1024;
    int* csr      = ip; ip += E;

    const int B = 256;
    dim3 gNode((N + 3) / 4);
    dim3 gE((E + B - 1) / B);
    dim3 gScan((N + 255) / 256);
    int nb = (N + 255) / 256;

    zeroInts<<<(2 * N + B - 1) / B, B, 0, stream>>>(deg, 2 * N);
    phaseA<<<gNode, B, 0, stream>>>(x, W1, a_src1, a_dst1, h1, asrc1, adst1, eloop1, N);
    degCount<<<gE, B, 0, stream>>>(dst, deg, E);
    scan1<<<gScan, 256, 0, stream>>>(deg, rowstart, blockSum, N);
    scan2<<<1, 1024, 0, stream>>>(blockSum, nb);
    scan3<<<gScan, 256, 0, stream>>>(rowstart, blockSum, N);
    scatter<<<gE, B, 0, stream>>>(src, dst, rowstart, cursor, csr, E);
    gatherL1<<<gNode, B, 0, stream>>>(csr, rowstart, deg, h1, asrc1, adst1, eloop1,
                                      b1, W2, a_src2, a_dst2,
                                      h2, asrc2, adst2, eloop2, N);
    gatherL2<<<gNode, B, 0, stream>>>(csr, rowstart, deg, h2, asrc2, adst2, eloop2,
                                      b2, out, N);
}